// Round 1
// baseline (217.610 us; speedup 1.0000x reference)
//
#include <hip/hip_runtime.h>
#include <hip/hip_bf16.h>

#define N_OBS 8192
#define N_TOP 128
#define N_DIM 64
#define BATCH 8192

typedef short bf16x8 __attribute__((ext_vector_type(8)));
typedef float f32x4 __attribute__((ext_vector_type(4)));

__device__ __forceinline__ float wave_sum(float v) {
#pragma unroll
  for (int off = 32; off; off >>= 1) v += __shfl_xor(v, off);
  return v;
}
__device__ __forceinline__ float wave_max(float v) {
#pragma unroll
  for (int off = 32; off; off >>= 1) v = fmaxf(v, __shfl_xor(v, off));
  return v;
}

// One wave computes gumbel-softmax over 128 topics for one row, then
// x[d] = sum_t s[t] * W[d][t] + b[d] for d = lane (64 dims, 64 lanes).
// WT: LDS [128][65] (padded: bank = (t + d) % 32, conflict-free both ways).
// sbuf: per-wave 128-float softmax scratch.
__device__ __forceinline__ float row_topic(const float* __restrict__ logits_row,
                                           const float* __restrict__ noise_row,
                                           const float* __restrict__ tb,
                                           const float* WT, float* sbuf, int lane) {
  float u0 = noise_row[lane], u1 = noise_row[lane + 64];
  // g = -log(-log(u + 1e-9) + 1e-9)
  float g0 = -__logf(-__logf(u0 + 1e-9f) + 1e-9f);
  float g1 = -__logf(-__logf(u1 + 1e-9f) + 1e-9f);
  float z0 = logits_row[lane] + g0;
  float z1 = logits_row[lane + 64] + g1;
  float m = wave_max(fmaxf(z0, z1));
  float e0 = __expf(z0 - m), e1 = __expf(z1 - m);
  float s = wave_sum(e0 + e1);
  float inv = __builtin_amdgcn_rcpf(s);
  sbuf[lane] = e0 * inv;
  sbuf[lane + 64] = e1 * inv;
  __syncthreads();  // uniform across all waves in every caller
  float acc = tb[lane];
#pragma unroll
  for (int t = 0; t < 128; t += 4) {
    float4 s4 = *(const float4*)(sbuf + t);  // same-address broadcast, free
    acc = fmaf(s4.x, WT[(t + 0) * 65 + lane], acc);
    acc = fmaf(s4.y, WT[(t + 1) * 65 + lane], acc);
    acc = fmaf(s4.z, WT[(t + 2) * 65 + lane], acc);
    acc = fmaf(s4.w, WT[(t + 3) * 65 + lane], acc);
  }
  return acc;
}

// Stage W (64x128 row-major) into LDS transposed [t][d], pad 65.
// Read coalesced; write bank = (65t + d) % 32 = (t + d) % 32, t consecutive
// across lanes -> conflict-free.
__device__ __forceinline__ void stage_wt(const float* __restrict__ topic_w, float* WT) {
  for (int idx = threadIdx.x; idx < 64 * 128; idx += 256) {
    int d = idx >> 7, t = idx & 127;
    WT[t * 65 + d] = topic_w[idx];
  }
}

// K1: x = topic(gumbel_softmax(logits, noise_full)); write x (bf16) and sq (f32).
__global__ __launch_bounds__(256) void build_x(const float* __restrict__ logits,
                                               const float* __restrict__ noise,
                                               const float* __restrict__ topic_w,
                                               const float* __restrict__ tb,
                                               __hip_bfloat16* __restrict__ xb,
                                               float* __restrict__ sq) {
  __shared__ float WT[128 * 65];
  __shared__ __align__(16) float sbuf[4][128];
  int tid = threadIdx.x, w = tid >> 6, lane = tid & 63;
  stage_wt(topic_w, WT);
  __syncthreads();
#pragma unroll
  for (int r = 0; r < 2; ++r) {
    int row = blockIdx.x * 8 + w * 2 + r;
    float xd = row_topic(logits + row * 128, noise + row * 128, tb, WT, sbuf[w], lane);
    xb[row * 64 + lane] = __float2bfloat16(xd);
    float s2 = wave_sum(xd * xd);
    if (lane == 0) sq[row] = s2;
  }
}

// K2: xi = topic(gs(logits[i], noise_i)), xj likewise; denom = 64 + ||xi-xj||^2.
__global__ __launch_bounds__(256) void build_denom(const float* __restrict__ logits,
                                                   const float* __restrict__ noise_i,
                                                   const float* __restrict__ noise_j,
                                                   const float* __restrict__ topic_w,
                                                   const float* __restrict__ tb,
                                                   const int* __restrict__ ii,
                                                   const int* __restrict__ jj,
                                                   float* __restrict__ denom) {
  __shared__ float WT[128 * 65];
  __shared__ __align__(16) float sbuf[4][128];
  __shared__ float xl[32][64];  // 32 row-tasks (16 batch elems x {i,j})
  int tid = threadIdx.x, w = tid >> 6, lane = tid & 63;
  stage_wt(topic_w, WT);
  __syncthreads();
  int b0 = blockIdx.x * 16;
#pragma unroll
  for (int it = 0; it < 8; ++it) {
    int task = it * 4 + w;
    int bl = task >> 1, side = task & 1;
    int b = b0 + bl;
    int row = side ? jj[b] : ii[b];
    const float* nz = (side ? noise_j : noise_i) + b * 128;
    float xd = row_topic(logits + row * 128, nz, tb, WT, sbuf[w], lane);
    xl[task][lane] = xd;
  }
  __syncthreads();
#pragma unroll
  for (int q = 0; q < 4; ++q) {
    int bl = w * 4 + q;
    float diff = xl[2 * bl][lane] - xl[2 * bl + 1][lane];
    float s2 = wave_sum(diff * diff);
    if (lane == 0) denom[b0 + bl] = 64.0f + s2;
  }
}

// K3: part_sum = sum over all pairs of 1/(1 + sq[m] + sq[n] - 2*x_m.x_n),
// bf16 MFMA Gram tiles. Block = 4 waves, block tile 128x128, wave tile 64x64
// (4x4 of 16x16x32 MFMAs, K=64 in 2 steps). Per-wave partial -> striped atomics.
__global__ __launch_bounds__(256) void pairwise(const unsigned short* __restrict__ xbp,
                                                const float* __restrict__ sq,
                                                float* __restrict__ partArr) {
  int w = threadIdx.x >> 6, lane = threadIdx.x & 63;
  int bi = blockIdx.x >> 6, bj = blockIdx.x & 63;
  int R = bi * 128 + (w >> 1) * 64;
  int C = bj * 128 + (w & 1) * 64;
  int r0 = lane & 15, kq = lane >> 4;

  bf16x8 A[4][2], B[4][2];
#pragma unroll
  for (int a = 0; a < 4; ++a)
#pragma unroll
    for (int s = 0; s < 2; ++s) {
      A[a][s] = *(const bf16x8*)(xbp + (R + a * 16 + r0) * 64 + s * 32 + kq * 8);
      B[a][s] = *(const bf16x8*)(xbp + (C + a * 16 + r0) * 64 + s * 32 + kq * 8);
    }

  f32x4 acc[4][4] = {};
#pragma unroll
  for (int a = 0; a < 4; ++a)
#pragma unroll
    for (int b = 0; b < 4; ++b) {
      acc[a][b] = __builtin_amdgcn_mfma_f32_16x16x32_bf16(A[a][0], B[b][0], acc[a][b], 0, 0, 0);
      acc[a][b] = __builtin_amdgcn_mfma_f32_16x16x32_bf16(A[a][1], B[b][1], acc[a][b], 0, 0, 0);
    }

  // C/D layout: col = lane&15, row = kq*4 + reg. (A transpose-swap would only
  // exchange m<->n which leaves the summed result invariant.)
  float m1[4][4], nsq[4];
#pragma unroll
  for (int a = 0; a < 4; ++a)
#pragma unroll
    for (int r = 0; r < 4; ++r) m1[a][r] = 1.0f + sq[R + a * 16 + kq * 4 + r];
#pragma unroll
  for (int b = 0; b < 4; ++b) nsq[b] = sq[C + b * 16 + r0];

  float local = 0.0f;
#pragma unroll
  for (int a = 0; a < 4; ++a)
#pragma unroll
    for (int b = 0; b < 4; ++b)
#pragma unroll
      for (int r = 0; r < 4; ++r) {
        float d = fmaf(-2.0f, acc[a][b][r], m1[a][r] + nsq[b]);
        local += __builtin_amdgcn_rcpf(d);
      }

  local = wave_sum(local);
  if (lane == 0) atomicAdd(partArr + (blockIdx.x & 63), local);
}

// K4: loss = pij * (log pij + log denom + log(part)), part = sum(slots) - 8192.
__global__ __launch_bounds__(256) void finalize(const float* __restrict__ pij,
                                                const float* __restrict__ denom,
                                                const float* __restrict__ partArr,
                                                float* __restrict__ out) {
  int b = blockIdx.x * 256 + threadIdx.x;
  float ps = 0.0f;
#pragma unroll
  for (int k = 0; k < 64; ++k) ps += partArr[k];
  float part = ps - 8192.0f;  // diagonal terms (==1 each) cancel exactly
  out[b] = pij[b] * (__logf(pij[b]) + __logf(denom[b]) + __logf(part));
}

extern "C" void kernel_launch(void* const* d_in, const int* in_sizes, int n_in,
                              void* d_out, int out_size, void* d_ws, size_t ws_size,
                              hipStream_t stream) {
  const float* pij     = (const float*)d_in[0];
  const float* noise_f = (const float*)d_in[1];
  const float* noise_i = (const float*)d_in[2];
  const float* noise_j = (const float*)d_in[3];
  const float* logits  = (const float*)d_in[4];
  const float* topic_w = (const float*)d_in[5];
  const float* tb      = (const float*)d_in[6];
  const int*   ii      = (const int*)d_in[7];
  const int*   jj      = (const int*)d_in[8];
  float* out = (float*)d_out;

  char* ws = (char*)d_ws;
  float* partArr = (float*)ws;                                   // 64 f32 slots
  __hip_bfloat16* xb = (__hip_bfloat16*)(ws + 1024);             // 8192*64 bf16 = 1 MB
  float* sq    = (float*)(ws + 1024 + N_OBS * N_DIM * 2);        // 8192 f32
  float* denom = (float*)(ws + 1024 + N_OBS * N_DIM * 2 + N_OBS * 4);  // 8192 f32

  hipMemsetAsync(partArr, 0, 64 * sizeof(float), stream);
  build_x<<<1024, 256, 0, stream>>>(logits, noise_f, topic_w, tb, xb, sq);
  build_denom<<<512, 256, 0, stream>>>(logits, noise_i, noise_j, topic_w, tb, ii, jj, denom);
  pairwise<<<4096, 256, 0, stream>>>((const unsigned short*)xb, sq, partArr);
  finalize<<<32, 256, 0, stream>>>(pij, denom, partArr, out);
}

// Round 3
// 123.734 us; speedup vs baseline: 1.7587x; 1.7587x over previous
//
#include <hip/hip_runtime.h>
#include <hip/hip_bf16.h>

// R3: fix R2's NaN — cross-lane LDS round-trip in the row engine had no
// barrier; compiler may reorder ds_read above ds_write (SIMT alias analysis
// can't see cross-lane deps). Restructured: each lane computes the softmax
// chunks it feeds to MFMA itself -> zero LDS, zero barriers, register-only.
// sq now computed from bf16-rounded x for exact consistency with the Gram dot.

typedef short bf16x8 __attribute__((ext_vector_type(8)));
typedef float f32x4 __attribute__((ext_vector_type(4)));

__device__ __forceinline__ float wave_sum(float v) {
#pragma unroll
  for (int off = 32; off; off >>= 1) v += __shfl_xor(v, off);
  return v;
}

__device__ __forceinline__ unsigned short f2bf(float x) {  // RNE, finite inputs
  union { float f; unsigned u; } v; v.f = x;
  return (unsigned short)((v.u + 0x7fffu + ((v.u >> 16) & 1u)) >> 16);
}
__device__ __forceinline__ float bf2f(unsigned short h) {
  union { float f; unsigned u; } v; v.u = ((unsigned)h) << 16;
  return v.f;
}

// One wave: gumbel-softmax for 16 rows (K=128) -> A-fragments in-register ->
// acc += S @ W^T (16 MFMAs). lgp/nzp are pre-offset to (row, part*8): lane
// (r,part) covers columns ks*32 + part*8 + j, exactly its A-fragment slices.
// Cross-lane traffic = softmax denominator only (shfl_xor, no LDS).
// No max-subtraction: z = logits+g <= ~22, exp safe in fp32.
__device__ __forceinline__ void gumbel_mfma(const float* __restrict__ lgp,
                                            const float* __restrict__ nzp,
                                            const bf16x8 Bf[4][4], f32x4 acc[4]) {
  float e[32];
  float ps = 0.0f;
#pragma unroll
  for (int ks = 0; ks < 4; ++ks) {
#pragma unroll
    for (int h = 0; h < 2; ++h) {
      float4 L = *(const float4*)(lgp + ks * 32 + h * 4);
      float4 U = *(const float4*)(nzp + ks * 32 + h * 4);
      float lv[4] = {L.x, L.y, L.z, L.w};
      float uv[4] = {U.x, U.y, U.z, U.w};
#pragma unroll
      for (int j = 0; j < 4; ++j) {
        float g = -__logf(-__logf(uv[j] + 1e-9f) + 1e-9f);
        float ev = __expf(lv[j] + g);
        e[ks * 8 + h * 4 + j] = ev;
        ps += ev;
      }
    }
  }
  // lane covers 32 of row r's 128 cols; full row sum = reduce across parts
  ps += __shfl_xor(ps, 16);
  ps += __shfl_xor(ps, 32);
  float inv = __builtin_amdgcn_rcpf(ps);
#pragma unroll
  for (int ks = 0; ks < 4; ++ks) {
    union { bf16x8 v; unsigned short s[8]; } pk;
#pragma unroll
    for (int j = 0; j < 8; ++j) pk.s[j] = f2bf(e[ks * 8 + j] * inv);
#pragma unroll
    for (int nt = 0; nt < 4; ++nt)
      acc[nt] = __builtin_amdgcn_mfma_f32_16x16x32_bf16(pk.v, Bf[nt][ks], acc[nt], 0, 0, 0);
  }
}

// grid 256 x 256 threads. wid even -> x-type (16 rows of x), wid odd ->
// pair-type (xi,xj in-wave -> denom; bias cancels in the difference).
__global__ __launch_bounds__(256) void row_engine(
    const float* __restrict__ logits, const float* __restrict__ noise_f,
    const float* __restrict__ noise_i, const float* __restrict__ noise_j,
    const float* __restrict__ topic_w, const float* __restrict__ tb,
    const int* __restrict__ ii, const int* __restrict__ jj,
    unsigned short* __restrict__ xb, float* __restrict__ sq,
    float* __restrict__ denomS) {
  int w = threadIdx.x >> 6, lane = threadIdx.x & 63;
  int r = lane & 15, part = lane >> 4;
  int wid = blockIdx.x * 4 + w;

  // B fragments (held whole kernel): lane (r,part) holds, for step ks,
  // B[k = ks*32 + part*8 + j][n = nt*16 + r] = topic_w[n*128 + k]
  // (same B-convention the R1 Gram kernel validated end-to-end).
  bf16x8 Bf[4][4];
#pragma unroll
  for (int nt = 0; nt < 4; ++nt) {
    const float* wp = topic_w + (nt * 16 + r) * 128 + part * 8;
#pragma unroll
    for (int ks = 0; ks < 4; ++ks) {
      float4 w0 = *(const float4*)(wp + ks * 32);
      float4 w1 = *(const float4*)(wp + ks * 32 + 4);
      union { bf16x8 v; unsigned short s[8]; } pk;
      pk.s[0] = f2bf(w0.x); pk.s[1] = f2bf(w0.y); pk.s[2] = f2bf(w0.z); pk.s[3] = f2bf(w0.w);
      pk.s[4] = f2bf(w1.x); pk.s[5] = f2bf(w1.y); pk.s[6] = f2bf(w1.z); pk.s[7] = f2bf(w1.w);
      Bf[nt][ks] = pk.v;
    }
  }
  int grp = wid >> 1;
  if ((wid & 1) == 0) {
    // x-type: rows g16..g16+15. C-layout: row m = part*4+g, col n = nt*16+r.
    int g16 = grp * 16;
    float tbv[4];
#pragma unroll
    for (int nt = 0; nt < 4; ++nt) tbv[nt] = tb[nt * 16 + r];
    f32x4 acc[4] = {};
    gumbel_mfma(logits + (g16 + r) * 128 + part * 8,
                noise_f + (g16 + r) * 128 + part * 8, Bf, acc);
    float sqp[4] = {0.f, 0.f, 0.f, 0.f};
#pragma unroll
    for (int nt = 0; nt < 4; ++nt)
#pragma unroll
      for (int g = 0; g < 4; ++g) {
        unsigned short hb = f2bf(acc[nt][g] + tbv[nt]);
        xb[(g16 + part * 4 + g) * 64 + nt * 16 + r] = hb;
        float xr = bf2f(hb);  // rounded value -> sq consistent with Gram dot
        sqp[g] += xr * xr;
      }
#pragma unroll
    for (int m = 1; m < 16; m <<= 1)
#pragma unroll
      for (int g = 0; g < 4; ++g) sqp[g] += __shfl_xor(sqp[g], m);
    if (r == 0) {
#pragma unroll
      for (int g = 0; g < 4; ++g) sq[g16 + part * 4 + g] = sqp[g];
    }
  } else {
    // pair-type: batch elems b0..b0+15; denom = 64 + ||xi-xj||^2 (fp32 diff).
    int b0 = grp * 16;
    int rowi = ii[b0 + r], rowj = jj[b0 + r];
    f32x4 ai[4] = {}, aj[4] = {};
    gumbel_mfma(logits + rowi * 128 + part * 8,
                noise_i + (b0 + r) * 128 + part * 8, Bf, ai);
    gumbel_mfma(logits + rowj * 128 + part * 8,
                noise_j + (b0 + r) * 128 + part * 8, Bf, aj);
    float dp[4] = {0.f, 0.f, 0.f, 0.f};
#pragma unroll
    for (int nt = 0; nt < 4; ++nt)
#pragma unroll
      for (int g = 0; g < 4; ++g) {
        float d = ai[nt][g] - aj[nt][g];
        dp[g] += d * d;
      }
#pragma unroll
    for (int m = 1; m < 16; m <<= 1)
#pragma unroll
      for (int g = 0; g < 4; ++g) dp[g] += __shfl_xor(dp[g], m);
    if (r == 0) {
#pragma unroll
      for (int g = 0; g < 4; ++g) denomS[b0 + part * 4 + g] = 64.0f + dp[g];
    }
  }
}

// Triangular pairwise: 2080 blocks = tiles (bi<=bj). Per-wave 64x64 tile,
// strict m<n only; per-wave partial slot (no atomics, no barriers).
__global__ __launch_bounds__(256) void pairwise(const unsigned short* __restrict__ xbp,
                                                const float* __restrict__ sq,
                                                float* __restrict__ partial) {
  int w = threadIdx.x >> 6, lane = threadIdx.x & 63;
  int t = blockIdx.x, bi = 0;
  while (t >= 64 - bi) { t -= 64 - bi; ++bi; }  // uniform scalar decode
  int bj = bi + t;
  int wr = w >> 1, wc = w & 1;
  bool diag = (bi == bj);
  float local = 0.0f;
  if (!(diag && wr > wc)) {  // lower-left wave of a diag block contributes 0
    int R = bi * 128 + wr * 64;
    int C = bj * 128 + wc * 64;
    int r0 = lane & 15, kq = lane >> 4;

    bf16x8 A[4][2], B[4][2];
#pragma unroll
    for (int a = 0; a < 4; ++a)
#pragma unroll
      for (int s = 0; s < 2; ++s) {
        A[a][s] = *(const bf16x8*)(xbp + (R + a * 16 + r0) * 64 + s * 32 + kq * 8);
        B[a][s] = *(const bf16x8*)(xbp + (C + a * 16 + r0) * 64 + s * 32 + kq * 8);
      }
    f32x4 acc[4][4] = {};
#pragma unroll
    for (int a = 0; a < 4; ++a)
#pragma unroll
      for (int b = 0; b < 4; ++b) {
        acc[a][b] = __builtin_amdgcn_mfma_f32_16x16x32_bf16(A[a][0], B[b][0], acc[a][b], 0, 0, 0);
        acc[a][b] = __builtin_amdgcn_mfma_f32_16x16x32_bf16(A[a][1], B[b][1], acc[a][b], 0, 0, 0);
      }
    float m1[4][4], nsq[4];
#pragma unroll
    for (int a = 0; a < 4; ++a)
#pragma unroll
      for (int g = 0; g < 4; ++g) m1[a][g] = 1.0f + sq[R + a * 16 + kq * 4 + g];
#pragma unroll
    for (int b = 0; b < 4; ++b) nsq[b] = sq[C + b * 16 + r0];

    if (diag && wr == wc) {  // 64x64 tile straddling the diagonal: keep r<c only
#pragma unroll
      for (int a = 0; a < 4; ++a)
#pragma unroll
        for (int b = 0; b < 4; ++b)
#pragma unroll
          for (int g = 0; g < 4; ++g) {
            float d = fmaf(-2.0f, acc[a][b][g], m1[a][g] + nsq[b]);
            int rl = a * 16 + kq * 4 + g, cl = b * 16 + r0;
            local += (rl < cl) ? __builtin_amdgcn_rcpf(d) : 0.0f;
          }
    } else {
#pragma unroll
      for (int a = 0; a < 4; ++a)
#pragma unroll
        for (int b = 0; b < 4; ++b)
#pragma unroll
          for (int g = 0; g < 4; ++g) {
            float d = fmaf(-2.0f, acc[a][b][g], m1[a][g] + nsq[b]);
            local += __builtin_amdgcn_rcpf(d);
          }
    }
  }
  local = wave_sum(local);
  if (lane == 0) partial[blockIdx.x * 4 + w] = local;  // every slot written
}

// part = 2 * sum_{m<n} rcp = (ref's full sum incl. diagonal) - 8192 exactly.
__global__ __launch_bounds__(256) void finalize(const float* __restrict__ pij,
                                                const float* __restrict__ denomS,
                                                const float* __restrict__ partial,
                                                float* __restrict__ out) {
  __shared__ float red[4];
  int tid = threadIdx.x, w = tid >> 6, lane = tid & 63;
  float ps = 0.0f;
  for (int k = tid; k < 2080 * 4; k += 256) ps += partial[k];
  ps = wave_sum(ps);
  if (lane == 0) red[w] = ps;
  __syncthreads();
  float part = 2.0f * (red[0] + red[1] + red[2] + red[3]);
  int b = blockIdx.x * 256 + tid;
  float p = pij[b];
  out[b] = p * (__logf(p) + __logf(denomS[b]) + __logf(part));
}

extern "C" void kernel_launch(void* const* d_in, const int* in_sizes, int n_in,
                              void* d_out, int out_size, void* d_ws, size_t ws_size,
                              hipStream_t stream) {
  const float* pij     = (const float*)d_in[0];
  const float* noise_f = (const float*)d_in[1];
  const float* noise_i = (const float*)d_in[2];
  const float* noise_j = (const float*)d_in[3];
  const float* logits  = (const float*)d_in[4];
  const float* topic_w = (const float*)d_in[5];
  const float* tb      = (const float*)d_in[6];
  const int*   ii      = (const int*)d_in[7];
  const int*   jj      = (const int*)d_in[8];
  float* out = (float*)d_out;

  char* ws = (char*)d_ws;
  float* partial     = (float*)ws;                                 // 8320 f32
  unsigned short* xb = (unsigned short*)(ws + 33280);              // 8192*64 bf16 = 1 MB
  float* sq          = (float*)(ws + 33280 + 1048576);             // 8192 f32
  float* denomS      = (float*)(ws + 33280 + 1048576 + 32768);     // 8192 f32

  row_engine<<<256, 256, 0, stream>>>(logits, noise_f, noise_i, noise_j,
                                      topic_w, tb, ii, jj, xb, sq, denomS);
  pairwise<<<2080, 256, 0, stream>>>(xb, sq, partial);
  finalize<<<32, 256, 0, stream>>>(pij, denomS, partial, out);
}